// Round 3
// baseline (276.130 us; speedup 1.0000x reference)
//
#include <hip/hip_runtime.h>

// Problem constants (from reference setup_inputs)
#define BATCH   4
#define CH      256
#define FH      200
#define FW      200
#define NROI    1024
#define PLANE   (FH * FW)      // 40000
#define POOL    7              // pooled output 7x7
#define SAMP    8              // sample grid 8x8 (AH = AW = 8)
#define CGROUPS 8              // channel-group blocks per roi
#define CH_PER_WAVE 8          // 4 waves/block * 8 groups * 8 = 256 channels

// wave = (roi, 8 channels), lane = sample point (ph, pw) in the 8x8 grid.
// Bilinear weights (validity + 0.25 pool scale folded in) computed once per
// lane; 4 gather instructions per channel; 2x2 avg-pool via two shfl_down;
// 49/64 lanes store. Full unroll -> all 32 gathers issue before the
// dependent math (memory-level parallelism); non-temporal stores keep the
// write-once output out of L2.
__global__ __launch_bounds__(256) void roialign_avg_kernel(
    const float* __restrict__ feat,   // (B, C, H, W) f32
    const float* __restrict__ rois,   // (N, 5) f32
    const float* __restrict__ scale_p,
    float* __restrict__ out)          // (N, C, 7, 7) f32
{
    const int n    = blockIdx.x;
    const int g    = blockIdx.y;
    const int tid  = threadIdx.x;
    const int wave = tid >> 6;
    const int lane = tid & 63;
    const int ph   = lane >> 3;   // sample row 0..7
    const int pw   = lane & 7;    // sample col 0..7

    const float scale = scale_p[0];
    const int   b  = (int)rois[n * 5 + 0];
    const float x1 = rois[n * 5 + 1] * scale;
    const float y1 = rois[n * 5 + 2] * scale;
    const float x2 = rois[n * 5 + 3] * scale;
    const float y2 = rois[n * 5 + 4] * scale;

    // matches reference: max(span+1, 0) / (AH-1)
    const float bin_h = fmaxf(y2 - y1 + 1.0f, 0.0f) / 7.0f;
    const float bin_w = fmaxf(x2 - x1 + 1.0f, 0.0f) / 7.0f;

    // Per-lane sample geometry (fixed across channels)
    const float h    = y1 + (float)ph * bin_h;
    const float w    = x1 + (float)pw * bin_w;
    const float hs_f = fminf(floorf(h), (float)(FH - 2));
    const float ws_f = fminf(floorf(w), (float)(FW - 2));
    const float hr   = h - hs_f;             // may exceed [0,1] at edges (ref does too)
    const float wr   = w - ws_f;
    const int   hi   = (int)fmaxf(hs_f, 0.0f);   // in [0,198] -> loads always in-bounds
    const int   wi   = (int)fmaxf(ws_f, 0.0f);   // in [0,198]
    const bool  valid = (h >= 0.0f) && (h < (float)FH) &&
                        (w >= 0.0f) && (w < (float)FW);
    const float m = valid ? 0.25f : 0.0f;    // fold validity + pool scale into weights

    const float w00 = (1.0f - hr) * (1.0f - wr) * m;
    const float w01 = (1.0f - hr) * wr * m;
    const float w10 = hr * (1.0f - wr) * m;
    const float w11 = hr * wr * m;

    // This wave's first channel
    const int c0 = g * (4 * CH_PER_WAVE) + wave * CH_PER_WAVE;

    const float* p = feat + ((size_t)(b * CH + c0)) * PLANE
                          + (size_t)(hi * FW + wi);
    float* outp = out + ((size_t)n * CH + c0) * (POOL * POOL) + ph * POOL + pw;

    const bool do_store = (ph < POOL) && (pw < POOL);

#pragma unroll
    for (int dc = 0; dc < CH_PER_WAVE; ++dc) {
        const float g00 = p[0];
        const float g01 = p[1];
        const float g10 = p[FW];
        const float g11 = p[FW + 1];
        // v = 0.25 * mask * bilinear(sample)
        float v = g00 * w00 + g01 * w01 + g10 * w10 + g11 * w11;

        // 2x2 avg-pool across the sample grid: lanes l, l+1, l+8, l+9
        float s1 = v + __shfl_down(v, 1, 64);
        float s2 = s1 + __shfl_down(s1, 8, 64);

        if (do_store) __builtin_nontemporal_store(s2, outp);

        p    += PLANE;
        outp += POOL * POOL;
    }
}

extern "C" void kernel_launch(void* const* d_in, const int* in_sizes, int n_in,
                              void* d_out, int out_size, void* d_ws, size_t ws_size,
                              hipStream_t stream) {
    const float* feat    = (const float*)d_in[0];  // (4,256,200,200) f32
    const float* rois    = (const float*)d_in[1];  // (1024,5) f32
    const float* scale_p = (const float*)d_in[2];  // scalar f32
    float*       out     = (float*)d_out;          // (1024,256,7,7) f32
    (void)in_sizes; (void)n_in; (void)out_size; (void)d_ws; (void)ws_size;

    dim3 grid(NROI, CGROUPS);
    dim3 block(256);
    hipLaunchKernelGGL(roialign_avg_kernel, grid, block, 0, stream,
                       feat, rois, scale_p, out);
}

// Round 4
// 271.484 us; speedup vs baseline: 1.0171x; 1.0171x over previous
//
#include <hip/hip_runtime.h>

// Problem constants (from reference setup_inputs)
#define BATCH   4
#define CH      256
#define FH      200
#define FW      200
#define NROI    1024
#define PLANE   (FH * FW)      // 40000
#define POOL    7              // pooled output 7x7
#define SAMP    8              // sample grid 8x8 (AH = AW = 8)
#define CGROUPS 8              // channel-group blocks per roi
#define CH_PER_WAVE 8          // 4 waves/block * 8 groups * 8 = 256 channels

// wave = (roi, 8 channels), lane = sample point (ph, pw) in the 8x8 grid.
// Two-phase body: issue ALL 32 gather loads (8 ch x 4 corners) into explicit
// register arrays, hard sched_barrier so the compiler cannot sink them back
// into the compute loop (baseline VGPR=12 proved it does), then weight +
// 2x2 shfl pool + non-temporal store. 32 loads in flight per wave -> 8x the
// memory-level parallelism of the baseline (which was latency-bound at
// 41% HBM BW, 7.5% VALUBusy).
__global__ __launch_bounds__(256) void roialign_avg_kernel(
    const float* __restrict__ feat,   // (B, C, H, W) f32
    const float* __restrict__ rois,   // (N, 5) f32
    const float* __restrict__ scale_p,
    float* __restrict__ out)          // (N, C, 7, 7) f32
{
    const int n    = blockIdx.x;
    const int g    = blockIdx.y;
    const int tid  = threadIdx.x;
    const int wave = tid >> 6;
    const int lane = tid & 63;
    const int ph   = lane >> 3;   // sample row 0..7
    const int pw   = lane & 7;    // sample col 0..7

    const float scale = scale_p[0];
    const int   b  = (int)rois[n * 5 + 0];
    const float x1 = rois[n * 5 + 1] * scale;
    const float y1 = rois[n * 5 + 2] * scale;
    const float x2 = rois[n * 5 + 3] * scale;
    const float y2 = rois[n * 5 + 4] * scale;

    // matches reference: max(span+1, 0) / (AH-1)
    const float bin_h = fmaxf(y2 - y1 + 1.0f, 0.0f) / 7.0f;
    const float bin_w = fmaxf(x2 - x1 + 1.0f, 0.0f) / 7.0f;

    // Per-lane sample geometry (fixed across channels)
    const float h    = y1 + (float)ph * bin_h;
    const float w    = x1 + (float)pw * bin_w;
    const float hs_f = fminf(floorf(h), (float)(FH - 2));
    const float ws_f = fminf(floorf(w), (float)(FW - 2));
    const float hr   = h - hs_f;             // may exceed [0,1] at edges (ref does too)
    const float wr   = w - ws_f;
    const int   hi   = (int)fmaxf(hs_f, 0.0f);   // [0,198] -> loads always in-bounds
    const int   wi   = (int)fmaxf(ws_f, 0.0f);   // [0,198]
    const bool  valid = (h >= 0.0f) && (h < (float)FH) &&
                        (w >= 0.0f) && (w < (float)FW);
    const float m = valid ? 0.25f : 0.0f;    // fold validity + pool scale into weights

    const float w00 = (1.0f - hr) * (1.0f - wr) * m;
    const float w01 = (1.0f - hr) * wr * m;
    const float w10 = hr * (1.0f - wr) * m;
    const float w11 = hr * wr * m;

    // This wave's first channel
    const int c0 = g * (4 * CH_PER_WAVE) + wave * CH_PER_WAVE;

    const float* p = feat + ((size_t)(b * CH + c0)) * PLANE
                          + (size_t)(hi * FW + wi);
    float* outp = out + ((size_t)n * CH + c0) * (POOL * POOL) + ph * POOL + pw;

    const bool do_store = (ph < POOL) && (pw < POOL);

    // -------- phase 1: issue all 32 gathers (static indices -> registers) ----
    float g00[CH_PER_WAVE], g01[CH_PER_WAVE], g10[CH_PER_WAVE], g11[CH_PER_WAVE];
#pragma unroll
    for (int dc = 0; dc < CH_PER_WAVE; ++dc) {
        const float* q = p + (size_t)dc * PLANE;
        g00[dc] = q[0];
        g01[dc] = q[1];
        g10[dc] = q[FW];
        g11[dc] = q[FW + 1];
    }
    // Hard fence: nothing below may be hoisted above, no load may sink below.
    __builtin_amdgcn_sched_barrier(0);

    // -------- phase 2: weight, 2x2 avg-pool via shuffles, store --------------
#pragma unroll
    for (int dc = 0; dc < CH_PER_WAVE; ++dc) {
        float v = g00[dc] * w00 + g01[dc] * w01 + g10[dc] * w10 + g11[dc] * w11;

        // 2x2 avg-pool across the sample grid: lanes l, l+1, l+8, l+9
        float s1 = v + __shfl_down(v, 1, 64);
        float s2 = s1 + __shfl_down(s1, 8, 64);

        if (do_store)
            __builtin_nontemporal_store(s2, outp + dc * (POOL * POOL));
    }
}

extern "C" void kernel_launch(void* const* d_in, const int* in_sizes, int n_in,
                              void* d_out, int out_size, void* d_ws, size_t ws_size,
                              hipStream_t stream) {
    const float* feat    = (const float*)d_in[0];  // (4,256,200,200) f32
    const float* rois    = (const float*)d_in[1];  // (1024,5) f32
    const float* scale_p = (const float*)d_in[2];  // scalar f32
    float*       out     = (float*)d_out;          // (1024,256,7,7) f32
    (void)in_sizes; (void)n_in; (void)out_size; (void)d_ws; (void)ws_size;

    dim3 grid(NROI, CGROUPS);
    dim3 block(256);
    hipLaunchKernelGGL(roialign_avg_kernel, grid, block, 0, stream,
                       feat, rois, scale_p, out);
}